// Round 9
// baseline (565.599 us; speedup 1.0000x reference)
//
#include <hip/hip_runtime.h>
#include <cstdint>

// FP32 external interface (reference is jnp.float32). Intermediates bf16 (u16),
// all accumulation fp32. R14: PER-BATCH PIPELINE {build, conv1, conv2} x2 --
// GroupNorm stats are per-batch so the batches are independent; sequencing them
// keeps each conv's random-gather pool (comb-b 102.4 MB / h1-b 51.2 MB) inside
// the 256-MB L3, freshly seeded by its producer kernel. h1 stores back to
// cacheable (they seed conv2's gathers). NT only on pure-stream inputs
// (x1/x2/nbr). comb-in-d_out aliasing stays safe under this order.

typedef unsigned short u16;
typedef u16 u16x8 __attribute__((ext_vector_type(8)));
typedef float f4 __attribute__((ext_vector_type(4)));
using s16x8 = __attribute__((ext_vector_type(8))) short;
using u16x4 = __attribute__((ext_vector_type(4))) u16;

#define EPS 1e-5f
#define BB 2
#define CIN 64
#define CH 32
#define SVOX 64000
#define NC 100000
#define NF 400000

static __device__ __forceinline__ float b2f(u16 h) {
    return __builtin_bit_cast(float, (unsigned)h << 16);
}
static __device__ __forceinline__ u16 f2b(float f) {
    unsigned u = __builtin_bit_cast(unsigned, f);
    u += 0x7FFFu + ((u >> 16) & 1u);
    return (u16)(u >> 16);
}
static __device__ __forceinline__ f4 mfma16(s16x8 a, s16x8 b, f4 c) {
    return __builtin_amdgcn_mfma_f32_16x16x32_bf16(a, b, c, 0, 0, 0);
}

// ---------------- prep: zero stats + build MFMA A-fragment weight tables -------
__global__ __launch_bounds__(256) void k_prep(
    const float* __restrict__ w1, const float* __restrict__ w2,
    float* __restrict__ stats, u16* __restrict__ wf1, u16* __restrict__ wf2)
{
    int t0 = blockIdx.x * 256 + threadIdx.x, stride = gridDim.x * 256;
    for (int i = t0; i < 12288; i += stride) stats[i] = 0.f;
    for (int i = t0; i < 14 * 2 * 512; i += stride) {
        int j = i & 7, l = (i >> 3) & 63, ot = (i >> 9) & 1, s = i >> 10;
        int k = s >> 1, h = s & 1;
        int c = h * 32 + (l >> 4) * 8 + j;
        int o = ot * 16 + (l & 15);
        wf1[i] = f2b(w1[(o * CIN + c) * 7 + k]);
    }
    for (int i = t0; i < 7 * 2 * 512; i += stride) {
        int j = i & 7, l = (i >> 3) & 63, ot = (i >> 9) & 1, k = i >> 10;
        int c = (l >> 4) * 8 + j;
        int o = ot * 16 + (l & 15);
        wf2[i] = f2b(w2[(o * CH + c) * 7 + k]);
    }
}

// ---------------- stage A: dense 1x1x1 conv (64 -> 32) + fused GN stats --------
__global__ __launch_bounds__(256) void k_reduce(
    const float* __restrict__ x1, const float* __restrict__ wr,
    u16* __restrict__ y, float* __restrict__ statsA)
{
    __shared__ float wl[CIN * CH];
    __shared__ float sred[64];
    int tid = threadIdx.x, b = blockIdx.y;
    if (tid < 64) sred[tid] = 0.f;
    for (int i = tid; i < CIN * CH; i += 256) {
        int c = i >> 5, o = i & 31;
        wl[i] = wr[o * CIN + c];   // wl[c][o]
    }
    __syncthreads();
    int s0 = blockIdx.x * 512 + tid;
    int s1 = s0 + 256;
    const float* xb = x1 + (size_t)b * CIN * SVOX;
    float acc0[CH], acc1[CH];
#pragma unroll
    for (int o = 0; o < CH; o++) { acc0[o] = 0.f; acc1[o] = 0.f; }
    for (int c = 0; c < CIN; c++) {
        float xv0 = __builtin_nontemporal_load(&xb[(size_t)c * SVOX + s0]);
        float xv1 = __builtin_nontemporal_load(&xb[(size_t)c * SVOX + s1]);
        const float* w = &wl[c * CH];
#pragma unroll
        for (int o = 0; o < CH; o++) {
            float wv = w[o];
            acc0[o] = fmaf(xv0, wv, acc0[o]);
            acc1[o] = fmaf(xv1, wv, acc1[o]);
        }
    }
    u16* y0 = y + ((size_t)b * SVOX + s0) * CH;
    u16* y1 = y + ((size_t)b * SVOX + s1) * CH;
#pragma unroll
    for (int g = 0; g < 4; g++) {
        u16x8 v0, v1;
#pragma unroll
        for (int i = 0; i < 8; i++) {
            v0[i] = f2b(acc0[g * 8 + i]);
            v1[i] = f2b(acc1[g * 8 + i]);
        }
        ((u16x8*)y0)[g] = v0;    // cacheable: k_build gathers y (8.2 MB pool)
        ((u16x8*)y1)[g] = v1;
    }
    // fused stats: wave butterfly per 8-channel group, then LDS + global atomics
    int lane = tid & 63;
#pragma unroll
    for (int g = 0; g < 4; g++) {
        float s[8], qq[8];
#pragma unroll
        for (int i = 0; i < 8; i++) {
            int o = g * 8 + i;
            s[i] = acc0[o] + acc1[o];
            qq[i] = fmaf(acc0[o], acc0[o], acc1[o] * acc1[o]);
        }
#pragma unroll
        for (int m = 1; m < 64; m <<= 1) {
#pragma unroll
            for (int i = 0; i < 8; i++) {
                s[i] += __shfl_xor(s[i], m);
                qq[i] += __shfl_xor(qq[i], m);
            }
        }
        if (lane == 0) {
#pragma unroll
            for (int i = 0; i < 8; i++) {
                atomicAdd(&sred[(g * 8 + i) * 2], s[i]);
                atomicAdd(&sred[(g * 8 + i) * 2 + 1], qq[i]);
            }
        }
    }
    __syncthreads();
    if (tid < 64) atomicAdd(&statsA[(size_t)(b * 64 + tid) * 32], sred[tid]);
}

// ---------------- build comb records [b][NF][64] bf16 (128 B each), one batch --
// ch 0..31 = x2 (transposed), ch 32..63 = relu(norm(y[sidx[uidx[n]]])).
// comb stores cacheable: they seed L3 for conv1's random gathers.
__global__ __launch_bounds__(256) void k_build(
    const float* __restrict__ x2, const u16* __restrict__ y,
    const float* __restrict__ statsA, const float* __restrict__ gA,
    const float* __restrict__ bA, const int* __restrict__ sidx,
    const int* __restrict__ uidx, u16* __restrict__ comb, int b)
{
    __shared__ u16 tile[64][40];
    __shared__ float sl[CH * 2];
    int tid = threadIdx.x;
    if (tid < CH) {
        float sum = statsA[(size_t)(b * 64 + tid * 2) * 32];
        float sq  = statsA[(size_t)(b * 64 + tid * 2 + 1) * 32];
        float mean = sum * (1.f / SVOX);
        float var = sq * (1.f / SVOX) - mean * mean;
        float sc = rsqrtf(var + EPS) * gA[tid];
        sl[tid * 2] = sc;
        sl[tid * 2 + 1] = bA[tid] - mean * sc;
    }
    int c = tid >> 3, no = (tid & 7) * 8;
    int nl = tid >> 3, seg = tid & 7;
    for (int t = blockIdx.x; t < 6250; t += gridDim.x) {
        int n0 = t * 64;
        const float* src = x2 + ((size_t)b * CH + c) * NF + n0 + no;
        f4 v0 = __builtin_nontemporal_load((const f4*)src);
        f4 v1 = __builtin_nontemporal_load((const f4*)(src + 4));
        __syncthreads();   // previous tile's phase-2 readers done (also: sl ready)
#pragma unroll
        for (int i = 0; i < 4; i++) tile[no + i][c] = f2b(v0[i]);
#pragma unroll
        for (int i = 0; i < 4; i++) tile[no + 4 + i][c] = f2b(v1[i]);
        __syncthreads();
#pragma unroll
        for (int it = 0; it < 2; it++) {
            int n = n0 + it * 32 + nl;
            u16x8 ov;
            if (seg < 4) {
                int co = seg * 8;
#pragma unroll
                for (int i = 0; i < 8; i++) ov[i] = tile[it * 32 + nl][co + i];
            } else {
                int u = uidx[(size_t)b * NF + n];
                int j = sidx[(size_t)b * NC + u];
                const u16x8* yr = (const u16x8*)(y + ((size_t)b * SVOX + j) * CH);
                u16x8 v = yr[seg - 4];
                int co = (seg - 4) * 8;
#pragma unroll
                for (int i = 0; i < 8; i++)
                    ov[i] = f2b(fmaxf(fmaf(b2f(v[i]), sl[(co + i) * 2], sl[(co + i) * 2 + 1]), 0.f));
            }
            *(u16x8*)(comb + ((size_t)b * NF + n) * 64 + seg * 8) = ov;
        }
    }
}

// ---------------- conv1: MFMA gather-GEMM over 128-B comb records, one batch ---
// out[n][o] = sum_{k,c} comb[nbr[n][k]][c] * w1[o][c][k]; fused stats1.
// comb-b (102.4 MB) is L3-resident from k_build; h1 stores cacheable (seed conv2).
__global__ __launch_bounds__(512) void k_conv1(
    const u16* __restrict__ comb, const u16* __restrict__ wfg,
    const int* __restrict__ nbr, u16* __restrict__ h1,
    float* __restrict__ stats1, int b)
{
    __shared__ u16 wf[14 * 2 * 512];   // 28 KB shared by 8 waves
    __shared__ float sst[64];
    int tid = threadIdx.x;
    if (tid < 64) sst[tid] = 0.f;
    const f4* wsrc = (const f4*)wfg;
    f4* wdst = (f4*)wf;
    for (int i = tid; i < 1792; i += 512) wdst[i] = wsrc[i];
    __syncthreads();
    const s16x8* wfv = (const s16x8*)wf;
    int lane = tid & 63, wave = tid >> 6;
    int p = lane & 15, q = lane >> 4;
    int n = blockIdx.x * 128 + wave * 16 + p;   // grid exact: 3125*128 == NF
    const u16* Cb = comb + (size_t)b * NF * 64;
    const int* nbb = nbr + ((size_t)b * NF + n) * 7;
    int i0[7];
#pragma unroll
    for (int k = 0; k < 7; k++) i0[k] = __builtin_nontemporal_load(&nbb[k]);
    s16x8 rlo[7], rhi[7];
#pragma unroll
    for (int k = 0; k < 7; k++) {
        const u16* rec = Cb + (size_t)i0[k] * 64;
        rlo[k] = __builtin_bit_cast(s16x8, *(const u16x8*)(rec + q * 8));
        rhi[k] = __builtin_bit_cast(s16x8, *(const u16x8*)(rec + 32 + q * 8));
    }
    f4 acc0 = {0.f, 0.f, 0.f, 0.f};
    f4 acc1 = {0.f, 0.f, 0.f, 0.f};
#pragma unroll
    for (int k = 0; k < 7; k++) {
        acc0 = mfma16(wfv[(k * 4 + 0) * 64 + lane], rlo[k], acc0);
        acc1 = mfma16(wfv[(k * 4 + 1) * 64 + lane], rlo[k], acc1);
        acc0 = mfma16(wfv[(k * 4 + 2) * 64 + lane], rhi[k], acc0);
        acc1 = mfma16(wfv[(k * 4 + 3) * 64 + lane], rhi[k], acc1);
    }
    // fused stats: reduce over the 16 particles (p) per channel, f32 pre-rounding
    float s[8], t[8];
#pragma unroll
    for (int r = 0; r < 4; r++) {
        s[r] = acc0[r];     t[r] = acc0[r] * acc0[r];
        s[4 + r] = acc1[r]; t[4 + r] = acc1[r] * acc1[r];
    }
#pragma unroll
    for (int m = 1; m < 16; m <<= 1) {
#pragma unroll
        for (int j = 0; j < 8; j++) {
            s[j] += __shfl_xor(s[j], m);
            t[j] += __shfl_xor(t[j], m);
        }
    }
    if (p == 0) {
#pragma unroll
        for (int r = 0; r < 4; r++) {
            atomicAdd(&sst[(q * 4 + r) * 2],       s[r]);
            atomicAdd(&sst[(q * 4 + r) * 2 + 1],   t[r]);
            atomicAdd(&sst[(16 + q * 4 + r) * 2],     s[4 + r]);
            atomicAdd(&sst[(16 + q * 4 + r) * 2 + 1], t[4 + r]);
        }
    }
    // D: col = lane&15 = particle, row = 4*q + r = output channel
    u16x4 v0, v1;
#pragma unroll
    for (int r = 0; r < 4; r++) { v0[r] = f2b(acc0[r]); v1[r] = f2b(acc1[r]); }
    u16* out = h1 + ((size_t)b * NF + n) * CH + q * 4;
    *(u16x4*)out = v0;
    *(u16x4*)(out + 16) = v1;
    __syncthreads();
    if (tid < 64) atomicAdd(&stats1[(size_t)(b * 64 + tid) * 32], sst[tid]);
}

// ---------------- conv2: gather-GEMM, fin1+norm1+relu fused, f32 out, one batch -
// h1-b (51.2 MB) is L3-resident from conv1-b.
__global__ __launch_bounds__(512) void k_conv2(
    const u16* __restrict__ x, const u16* __restrict__ wfg,
    const int* __restrict__ nbr, const float* __restrict__ stats1,
    const float* __restrict__ g1, const float* __restrict__ b1,
    float* __restrict__ out, float* __restrict__ stats2, int b)
{
    __shared__ u16 wf[7 * 2 * 512];   // 14 KB shared by 8 waves
    __shared__ float sst[64];
    int tid = threadIdx.x;
    if (tid < 64) sst[tid] = 0.f;
    const f4* wsrc = (const f4*)wfg;
    f4* wdst = (f4*)wf;
    for (int i = tid; i < 896; i += 512) wdst[i] = wsrc[i];
    __syncthreads();
    const s16x8* wfv = (const s16x8*)wf;
    int lane = tid & 63, wave = tid >> 6;
    int p = lane & 15, q = lane >> 4;
    int n = blockIdx.x * 128 + wave * 16 + p;
    const u16* Xb = x + (size_t)b * NF * CH;
    const int* nbb = nbr + ((size_t)b * NF + n) * 7;
    int i0[7];
#pragma unroll
    for (int k = 0; k < 7; k++) i0[k] = __builtin_nontemporal_load(&nbb[k]);
    // per-lane GN-1 finalize for this lane's 8 channels (L2-broadcast loads)
    float sc[8], sh[8];
#pragma unroll
    for (int j = 0; j < 8; j++) {
        int ch = q * 8 + j;
        float sum = stats1[(size_t)(b * 64 + ch * 2) * 32];
        float sq  = stats1[(size_t)(b * 64 + ch * 2 + 1) * 32];
        float mean = sum * (1.f / NF);
        float var = sq * (1.f / NF) - mean * mean;
        float s = rsqrtf(var + EPS) * g1[ch];
        sc[j] = s;
        sh[j] = b1[ch] - mean * s;
    }
    u16x8 raw[7];
#pragma unroll
    for (int k = 0; k < 7; k++)
        raw[k] = *(const u16x8*)(Xb + (size_t)i0[k] * CH + q * 8);
    f4 acc0 = {0.f, 0.f, 0.f, 0.f};
    f4 acc1 = {0.f, 0.f, 0.f, 0.f};
#pragma unroll
    for (int k = 0; k < 7; k++) {
        u16x8 nv;
#pragma unroll
        for (int j = 0; j < 8; j++)
            nv[j] = f2b(fmaxf(fmaf(b2f(raw[k][j]), sc[j], sh[j]), 0.f));
        s16x8 a = __builtin_bit_cast(s16x8, nv);
        acc0 = mfma16(wfv[(k * 2 + 0) * 64 + lane], a, acc0);
        acc1 = mfma16(wfv[(k * 2 + 1) * 64 + lane], a, acc1);
    }
    // fused stats2 on raw f32 conv output
    float s[8], t[8];
#pragma unroll
    for (int r = 0; r < 4; r++) {
        s[r] = acc0[r];     t[r] = acc0[r] * acc0[r];
        s[4 + r] = acc1[r]; t[4 + r] = acc1[r] * acc1[r];
    }
#pragma unroll
    for (int m = 1; m < 16; m <<= 1) {
#pragma unroll
        for (int j = 0; j < 8; j++) {
            s[j] += __shfl_xor(s[j], m);
            t[j] += __shfl_xor(t[j], m);
        }
    }
    if (p == 0) {
#pragma unroll
        for (int r = 0; r < 4; r++) {
            atomicAdd(&sst[(q * 4 + r) * 2],       s[r]);
            atomicAdd(&sst[(q * 4 + r) * 2 + 1],   t[r]);
            atomicAdd(&sst[(16 + q * 4 + r) * 2],     s[4 + r]);
            atomicAdd(&sst[(16 + q * 4 + r) * 2 + 1], t[4 + r]);
        }
    }
    // f32 transposed store: out[b][ch][n]
    float* ob = out + (size_t)b * CH * NF + n;
#pragma unroll
    for (int r = 0; r < 4; r++) {
        ob[(size_t)(q * 4 + r) * NF] = acc0[r];
        ob[(size_t)(16 + q * 4 + r) * NF] = acc1[r];
    }
    __syncthreads();
    if (tid < 64) atomicAdd(&stats2[(size_t)(b * 64 + tid) * 32], sst[tid]);
}

// ---------------- in-place fin2+normalize+relu on f32 [B][32][NF] ---------------
__global__ __launch_bounds__(256) void k_norm2c(
    float* __restrict__ h, const float* __restrict__ stats2,
    const float* __restrict__ g2, const float* __restrict__ b2)
{
    const int total = BB * CH * (NF / 4);   // 6,400,000 f4 elements
    for (int i4 = blockIdx.x * 256 + threadIdx.x; i4 < total; i4 += gridDim.x * 256) {
        int cf = i4 / (NF / 4);              // 0..63 = b*32 + c
        int o = cf & 31;
        float sum = stats2[(size_t)(cf * 2) * 32];
        float sq  = stats2[(size_t)(cf * 2 + 1) * 32];
        float mean = sum * (1.f / NF);
        float var = sq * (1.f / NF) - mean * mean;
        float sc = rsqrtf(var + EPS) * g2[o];
        float sh = b2[o] - mean * sc;
        f4 v = ((f4*)h)[i4];
#pragma unroll
        for (int j = 0; j < 4; j++) v[j] = fmaxf(fmaf(v[j], sc, sh), 0.f);
        ((f4*)h)[i4] = v;
    }
}

extern "C" void kernel_launch(void* const* d_in, const int* in_sizes, int n_in,
                              void* d_out, int out_size, void* d_ws, size_t ws_size,
                              hipStream_t stream)
{
    const float* x1 = (const float*)d_in[0];
    const float* x2 = (const float*)d_in[1];
    const float* wr = (const float*)d_in[2];
    const float* gA = (const float*)d_in[3];
    const float* bA = (const float*)d_in[4];
    const float* w1 = (const float*)d_in[5];
    const float* g1 = (const float*)d_in[6];
    const float* b1 = (const float*)d_in[7];
    const float* w2 = (const float*)d_in[8];
    const float* g2 = (const float*)d_in[9];
    const float* b2 = (const float*)d_in[10];
    const int* sidx = (const int*)d_in[11];
    const int* uidx = (const int*)d_in[12];
    const int* nbr  = (const int*)d_in[13];

    // comb [B][NF][64] bf16 = 102.4 MB lives in d_out; conv2-b overwrites exactly
    // comb-b's bytes (dead after conv1-b) under the per-batch order.
    // ws (~59.5 MB): h1 51.2 | y 8.19 | stats | wf tables.
    char* ws = (char*)d_ws;
    u16* h1      = (u16*)ws;                            // [B][NF][32] bf16
    u16* y       = (u16*)(ws + 51200000);               // [B][SVOX][32] bf16
    float* stats = (float*)(ws + 59392000);             // 3 x 16 KB padded accumulators
    float* statsA = stats;
    float* stats1 = (float*)(ws + 59392000 + 16384);
    float* stats2 = (float*)(ws + 59392000 + 32768);
    u16* wf1g = (u16*)(ws + 59392000 + 49152);          // 28672 B
    u16* wf2g = (u16*)(ws + 59392000 + 49152 + 28672);  // 14336 B
    u16* comb = (u16*)d_out;

    k_prep<<<48, 256, 0, stream>>>(w1, w2, stats, wf1g, wf2g);
    k_reduce<<<dim3(125, BB), 256, 0, stream>>>(x1, wr, y, statsA);
    for (int b = 0; b < BB; b++) {
        k_build<<<1024, 256, 0, stream>>>(x2, y, statsA, gA, bA, sidx, uidx, comb, b);
        k_conv1<<<3125, 512, 0, stream>>>(comb, wf1g, nbr, h1, stats1, b);
        k_conv2<<<3125, 512, 0, stream>>>(h1, wf2g, nbr, stats1, g1, b1, (float*)d_out, stats2, b);
    }
    k_norm2c<<<2048, 256, 0, stream>>>((float*)d_out, stats2, g2, b2);
}

// Round 10
// 538.266 us; speedup vs baseline: 1.0508x; 1.0508x over previous
//
#include <hip/hip_runtime.h>
#include <cstdint>

// FP32 external interface (reference is jnp.float32). Intermediates bf16 (u16),
// all accumulation fp32. R15: revert R14's per-batch conv pipeline (L2-miss
// refetch is XCD-structural, not capacity -- split gained nothing, cost 20us).
// New: conv2 writes bf16 h2 records (51.2 MB coalesced) instead of 409.6 MB
// strided f32; k_norm2t (R5-style LDS transpose) produces the f32 output.
// Output-chain traffic 1.23 GB -> 0.61 GB. h2 placement: b0 -> d_out top
// quarter (comb dead after conv1), b1 -> ws h1-b0 slot (dead after conv2-b0);
// norm2t-b0 consumed before norm2t-b1 overwrites -- launch-order safe.

typedef unsigned short u16;
typedef u16 u16x8 __attribute__((ext_vector_type(8)));
typedef float f4 __attribute__((ext_vector_type(4)));
using s16x8 = __attribute__((ext_vector_type(8))) short;
using u16x4 = __attribute__((ext_vector_type(4))) u16;

#define EPS 1e-5f
#define BB 2
#define CIN 64
#define CH 32
#define SVOX 64000
#define NC 100000
#define NF 400000

static __device__ __forceinline__ float b2f(u16 h) {
    return __builtin_bit_cast(float, (unsigned)h << 16);
}
static __device__ __forceinline__ u16 f2b(float f) {
    unsigned u = __builtin_bit_cast(unsigned, f);
    u += 0x7FFFu + ((u >> 16) & 1u);
    return (u16)(u >> 16);
}
static __device__ __forceinline__ f4 mfma16(s16x8 a, s16x8 b, f4 c) {
    return __builtin_amdgcn_mfma_f32_16x16x32_bf16(a, b, c, 0, 0, 0);
}

// ---------------- prep: zero stats + build MFMA A-fragment weight tables -------
__global__ __launch_bounds__(256) void k_prep(
    const float* __restrict__ w1, const float* __restrict__ w2,
    float* __restrict__ stats, u16* __restrict__ wf1, u16* __restrict__ wf2)
{
    int t0 = blockIdx.x * 256 + threadIdx.x, stride = gridDim.x * 256;
    for (int i = t0; i < 12288; i += stride) stats[i] = 0.f;
    for (int i = t0; i < 14 * 2 * 512; i += stride) {
        int j = i & 7, l = (i >> 3) & 63, ot = (i >> 9) & 1, s = i >> 10;
        int k = s >> 1, h = s & 1;
        int c = h * 32 + (l >> 4) * 8 + j;
        int o = ot * 16 + (l & 15);
        wf1[i] = f2b(w1[(o * CIN + c) * 7 + k]);
    }
    for (int i = t0; i < 7 * 2 * 512; i += stride) {
        int j = i & 7, l = (i >> 3) & 63, ot = (i >> 9) & 1, k = i >> 10;
        int c = (l >> 4) * 8 + j;
        int o = ot * 16 + (l & 15);
        wf2[i] = f2b(w2[(o * CH + c) * 7 + k]);
    }
}

// ---------------- stage A: dense 1x1x1 conv (64 -> 32) + fused GN stats --------
__global__ __launch_bounds__(256) void k_reduce(
    const float* __restrict__ x1, const float* __restrict__ wr,
    u16* __restrict__ y, float* __restrict__ statsA)
{
    __shared__ float wl[CIN * CH];
    __shared__ float sred[64];
    int tid = threadIdx.x, b = blockIdx.y;
    if (tid < 64) sred[tid] = 0.f;
    for (int i = tid; i < CIN * CH; i += 256) {
        int c = i >> 5, o = i & 31;
        wl[i] = wr[o * CIN + c];   // wl[c][o]
    }
    __syncthreads();
    int s0 = blockIdx.x * 512 + tid;
    int s1 = s0 + 256;
    const float* xb = x1 + (size_t)b * CIN * SVOX;
    float acc0[CH], acc1[CH];
#pragma unroll
    for (int o = 0; o < CH; o++) { acc0[o] = 0.f; acc1[o] = 0.f; }
    for (int c = 0; c < CIN; c++) {
        float xv0 = __builtin_nontemporal_load(&xb[(size_t)c * SVOX + s0]);
        float xv1 = __builtin_nontemporal_load(&xb[(size_t)c * SVOX + s1]);
        const float* w = &wl[c * CH];
#pragma unroll
        for (int o = 0; o < CH; o++) {
            float wv = w[o];
            acc0[o] = fmaf(xv0, wv, acc0[o]);
            acc1[o] = fmaf(xv1, wv, acc1[o]);
        }
    }
    u16* y0 = y + ((size_t)b * SVOX + s0) * CH;
    u16* y1 = y + ((size_t)b * SVOX + s1) * CH;
#pragma unroll
    for (int g = 0; g < 4; g++) {
        u16x8 v0, v1;
#pragma unroll
        for (int i = 0; i < 8; i++) {
            v0[i] = f2b(acc0[g * 8 + i]);
            v1[i] = f2b(acc1[g * 8 + i]);
        }
        ((u16x8*)y0)[g] = v0;    // cacheable: k_build gathers y (8.2 MB pool)
        ((u16x8*)y1)[g] = v1;
    }
    // fused stats: wave butterfly per 8-channel group, then LDS + global atomics
    int lane = tid & 63;
#pragma unroll
    for (int g = 0; g < 4; g++) {
        float s[8], qq[8];
#pragma unroll
        for (int i = 0; i < 8; i++) {
            int o = g * 8 + i;
            s[i] = acc0[o] + acc1[o];
            qq[i] = fmaf(acc0[o], acc0[o], acc1[o] * acc1[o]);
        }
#pragma unroll
        for (int m = 1; m < 64; m <<= 1) {
#pragma unroll
            for (int i = 0; i < 8; i++) {
                s[i] += __shfl_xor(s[i], m);
                qq[i] += __shfl_xor(qq[i], m);
            }
        }
        if (lane == 0) {
#pragma unroll
            for (int i = 0; i < 8; i++) {
                atomicAdd(&sred[(g * 8 + i) * 2], s[i]);
                atomicAdd(&sred[(g * 8 + i) * 2 + 1], qq[i]);
            }
        }
    }
    __syncthreads();
    if (tid < 64) atomicAdd(&statsA[(size_t)(b * 64 + tid) * 32], sred[tid]);
}

// ---------------- build comb records [B][NF][64] bf16 (128 B each) -------------
// ch 0..31 = x2 (transposed), ch 32..63 = relu(norm(y[sidx[uidx[n]]])).
__global__ __launch_bounds__(256) void k_build(
    const float* __restrict__ x2, const u16* __restrict__ y,
    const float* __restrict__ statsA, const float* __restrict__ gA,
    const float* __restrict__ bA, const int* __restrict__ sidx,
    const int* __restrict__ uidx, u16* __restrict__ comb)
{
    __shared__ u16 tile[64][40];
    __shared__ float sl[CH * 2];
    int tid = threadIdx.x, b = blockIdx.y;
    if (tid < CH) {
        float sum = statsA[(size_t)(b * 64 + tid * 2) * 32];
        float sq  = statsA[(size_t)(b * 64 + tid * 2 + 1) * 32];
        float mean = sum * (1.f / SVOX);
        float var = sq * (1.f / SVOX) - mean * mean;
        float sc = rsqrtf(var + EPS) * gA[tid];
        sl[tid * 2] = sc;
        sl[tid * 2 + 1] = bA[tid] - mean * sc;
    }
    int c = tid >> 3, no = (tid & 7) * 8;
    int nl = tid >> 3, seg = tid & 7;
    for (int t = blockIdx.x; t < 6250; t += gridDim.x) {
        int n0 = t * 64;
        const float* src = x2 + ((size_t)b * CH + c) * NF + n0 + no;
        f4 v0 = __builtin_nontemporal_load((const f4*)src);
        f4 v1 = __builtin_nontemporal_load((const f4*)(src + 4));
        __syncthreads();   // previous tile's phase-2 readers done (also: sl ready)
#pragma unroll
        for (int i = 0; i < 4; i++) tile[no + i][c] = f2b(v0[i]);
#pragma unroll
        for (int i = 0; i < 4; i++) tile[no + 4 + i][c] = f2b(v1[i]);
        __syncthreads();
#pragma unroll
        for (int it = 0; it < 2; it++) {
            int n = n0 + it * 32 + nl;
            u16x8 ov;
            if (seg < 4) {
                int co = seg * 8;
#pragma unroll
                for (int i = 0; i < 8; i++) ov[i] = tile[it * 32 + nl][co + i];
            } else {
                int u = uidx[(size_t)b * NF + n];
                int j = sidx[(size_t)b * NC + u];
                const u16x8* yr = (const u16x8*)(y + ((size_t)b * SVOX + j) * CH);
                u16x8 v = yr[seg - 4];
                int co = (seg - 4) * 8;
#pragma unroll
                for (int i = 0; i < 8; i++)
                    ov[i] = f2b(fmaxf(fmaf(b2f(v[i]), sl[(co + i) * 2], sl[(co + i) * 2 + 1]), 0.f));
            }
            *(u16x8*)(comb + ((size_t)b * NF + n) * 64 + seg * 8) = ov;
        }
    }
}

// ---------------- conv1: MFMA gather-GEMM over 128-B comb records ---------------
__global__ __launch_bounds__(512) void k_conv1(
    const u16* __restrict__ comb, const u16* __restrict__ wfg,
    const int* __restrict__ nbr, u16* __restrict__ h1,
    float* __restrict__ stats1)
{
    __shared__ u16 wf[14 * 2 * 512];   // 28 KB shared by 8 waves
    __shared__ float sst[64];
    int tid = threadIdx.x, b = blockIdx.y;
    if (tid < 64) sst[tid] = 0.f;
    const f4* wsrc = (const f4*)wfg;
    f4* wdst = (f4*)wf;
    for (int i = tid; i < 1792; i += 512) wdst[i] = wsrc[i];
    __syncthreads();
    const s16x8* wfv = (const s16x8*)wf;
    int lane = tid & 63, wave = tid >> 6;
    int p = lane & 15, q = lane >> 4;
    int n = blockIdx.x * 128 + wave * 16 + p;   // grid exact: 3125*128 == NF
    const u16* Cb = comb + (size_t)b * NF * 64;
    const int* nbb = nbr + ((size_t)b * NF + n) * 7;
    int i0[7];
#pragma unroll
    for (int k = 0; k < 7; k++) i0[k] = __builtin_nontemporal_load(&nbb[k]);
    s16x8 rlo[7], rhi[7];
#pragma unroll
    for (int k = 0; k < 7; k++) {
        const u16* rec = Cb + (size_t)i0[k] * 64;
        rlo[k] = __builtin_bit_cast(s16x8, *(const u16x8*)(rec + q * 8));
        rhi[k] = __builtin_bit_cast(s16x8, *(const u16x8*)(rec + 32 + q * 8));
    }
    f4 acc0 = {0.f, 0.f, 0.f, 0.f};
    f4 acc1 = {0.f, 0.f, 0.f, 0.f};
#pragma unroll
    for (int k = 0; k < 7; k++) {
        acc0 = mfma16(wfv[(k * 4 + 0) * 64 + lane], rlo[k], acc0);
        acc1 = mfma16(wfv[(k * 4 + 1) * 64 + lane], rlo[k], acc1);
        acc0 = mfma16(wfv[(k * 4 + 2) * 64 + lane], rhi[k], acc0);
        acc1 = mfma16(wfv[(k * 4 + 3) * 64 + lane], rhi[k], acc1);
    }
    // fused stats: reduce over the 16 particles (p) per channel, f32 pre-rounding
    float s[8], t[8];
#pragma unroll
    for (int r = 0; r < 4; r++) {
        s[r] = acc0[r];     t[r] = acc0[r] * acc0[r];
        s[4 + r] = acc1[r]; t[4 + r] = acc1[r] * acc1[r];
    }
#pragma unroll
    for (int m = 1; m < 16; m <<= 1) {
#pragma unroll
        for (int j = 0; j < 8; j++) {
            s[j] += __shfl_xor(s[j], m);
            t[j] += __shfl_xor(t[j], m);
        }
    }
    if (p == 0) {
#pragma unroll
        for (int r = 0; r < 4; r++) {
            atomicAdd(&sst[(q * 4 + r) * 2],       s[r]);
            atomicAdd(&sst[(q * 4 + r) * 2 + 1],   t[r]);
            atomicAdd(&sst[(16 + q * 4 + r) * 2],     s[4 + r]);
            atomicAdd(&sst[(16 + q * 4 + r) * 2 + 1], t[4 + r]);
        }
    }
    // D: col = lane&15 = particle, row = 4*q + r = output channel
    u16x4 v0, v1;
#pragma unroll
    for (int r = 0; r < 4; r++) { v0[r] = f2b(acc0[r]); v1[r] = f2b(acc1[r]); }
    u16* out = h1 + ((size_t)b * NF + n) * CH + q * 4;
    *(u16x4*)out = v0;
    *(u16x4*)(out + 16) = v1;
    __syncthreads();
    if (tid < 64) atomicAdd(&stats1[(size_t)(b * 64 + tid) * 32], sst[tid]);
}

// ---------------- conv2: gather-GEMM, fin1+norm1+relu fused, bf16 h2 out --------
// One batch per launch (h2 placement differs per batch). Writes coalesced 64-B
// bf16 records instead of 409.6 MB strided f32; fused stats2 on f32 accums.
__global__ __launch_bounds__(512) void k_conv2(
    const u16* __restrict__ x, const u16* __restrict__ wfg,
    const int* __restrict__ nbr, const float* __restrict__ stats1,
    const float* __restrict__ g1, const float* __restrict__ b1,
    u16* __restrict__ h2, float* __restrict__ stats2, int b)
{
    __shared__ u16 wf[7 * 2 * 512];   // 14 KB shared by 8 waves
    __shared__ float sst[64];
    int tid = threadIdx.x;
    if (tid < 64) sst[tid] = 0.f;
    const f4* wsrc = (const f4*)wfg;
    f4* wdst = (f4*)wf;
    for (int i = tid; i < 896; i += 512) wdst[i] = wsrc[i];
    __syncthreads();
    const s16x8* wfv = (const s16x8*)wf;
    int lane = tid & 63, wave = tid >> 6;
    int p = lane & 15, q = lane >> 4;
    int n = blockIdx.x * 128 + wave * 16 + p;
    const u16* Xb = x + (size_t)b * NF * CH;
    const int* nbb = nbr + ((size_t)b * NF + n) * 7;
    int i0[7];
#pragma unroll
    for (int k = 0; k < 7; k++) i0[k] = __builtin_nontemporal_load(&nbb[k]);
    // per-lane GN-1 finalize for this lane's 8 channels (L2-broadcast loads)
    float sc[8], sh[8];
#pragma unroll
    for (int j = 0; j < 8; j++) {
        int ch = q * 8 + j;
        float sum = stats1[(size_t)(b * 64 + ch * 2) * 32];
        float sq  = stats1[(size_t)(b * 64 + ch * 2 + 1) * 32];
        float mean = sum * (1.f / NF);
        float var = sq * (1.f / NF) - mean * mean;
        float s = rsqrtf(var + EPS) * g1[ch];
        sc[j] = s;
        sh[j] = b1[ch] - mean * s;
    }
    u16x8 raw[7];
#pragma unroll
    for (int k = 0; k < 7; k++)
        raw[k] = *(const u16x8*)(Xb + (size_t)i0[k] * CH + q * 8);
    f4 acc0 = {0.f, 0.f, 0.f, 0.f};
    f4 acc1 = {0.f, 0.f, 0.f, 0.f};
#pragma unroll
    for (int k = 0; k < 7; k++) {
        u16x8 nv;
#pragma unroll
        for (int j = 0; j < 8; j++)
            nv[j] = f2b(fmaxf(fmaf(b2f(raw[k][j]), sc[j], sh[j]), 0.f));
        s16x8 a = __builtin_bit_cast(s16x8, nv);
        acc0 = mfma16(wfv[(k * 2 + 0) * 64 + lane], a, acc0);
        acc1 = mfma16(wfv[(k * 2 + 1) * 64 + lane], a, acc1);
    }
    // fused stats2 on raw f32 conv output
    float s[8], t[8];
#pragma unroll
    for (int r = 0; r < 4; r++) {
        s[r] = acc0[r];     t[r] = acc0[r] * acc0[r];
        s[4 + r] = acc1[r]; t[4 + r] = acc1[r] * acc1[r];
    }
#pragma unroll
    for (int m = 1; m < 16; m <<= 1) {
#pragma unroll
        for (int j = 0; j < 8; j++) {
            s[j] += __shfl_xor(s[j], m);
            t[j] += __shfl_xor(t[j], m);
        }
    }
    if (p == 0) {
#pragma unroll
        for (int r = 0; r < 4; r++) {
            atomicAdd(&sst[(q * 4 + r) * 2],       s[r]);
            atomicAdd(&sst[(q * 4 + r) * 2 + 1],   t[r]);
            atomicAdd(&sst[(16 + q * 4 + r) * 2],     s[4 + r]);
            atomicAdd(&sst[(16 + q * 4 + r) * 2 + 1], t[4 + r]);
        }
    }
    // bf16 record store: h2[n][32]
    u16x4 v0, v1;
#pragma unroll
    for (int r = 0; r < 4; r++) { v0[r] = f2b(acc0[r]); v1[r] = f2b(acc1[r]); }
    u16* outp = h2 + (size_t)n * CH + q * 4;
    *(u16x4*)outp = v0;
    *(u16x4*)(outp + 16) = v1;
    __syncthreads();
    if (tid < 64) atomicAdd(&stats2[(size_t)(b * 64 + tid) * 32], sst[tid]);
}

// ---------------- norm2t: fin2+normalize+relu+transpose -> f32 [32][NF] ---------
// One batch per launch (read/write aliasing resolved by launch order).
__global__ __launch_bounds__(256) void k_norm2t(
    const u16* __restrict__ h2, const float* __restrict__ stats2,
    const float* __restrict__ g2, const float* __restrict__ b2,
    float* __restrict__ out, int b)
{
    __shared__ float sl[64];
    __shared__ float tile[CH][72];
    int tid = threadIdx.x;
    if (tid < CH) {
        float sum = stats2[(size_t)(b * 64 + tid * 2) * 32];
        float sq  = stats2[(size_t)(b * 64 + tid * 2 + 1) * 32];
        float mean = sum * (1.f / NF);
        float var = sq * (1.f / NF) - mean * mean;
        float sc = rsqrtf(var + EPS) * g2[tid];
        sl[tid * 2] = sc;
        sl[tid * 2 + 1] = b2[tid] - mean * sc;
    }
    int p = tid >> 2, c0 = (tid & 3) * 8;
    int c = tid >> 3, p0 = (tid & 7) * 8;
    float* ob = out + (size_t)b * CH * NF;
    for (int t = blockIdx.x; t < 6250; t += gridDim.x) {
        int n0 = t * 64;
        u16x8 v = *(const u16x8*)(h2 + (size_t)(n0 + p) * CH + c0);
        __syncthreads();   // prev tile's phase-2 readers done (also: sl ready)
#pragma unroll
        for (int i = 0; i < 8; i++) {
            int cc = c0 + i;
            tile[cc][p] = fmaxf(fmaf(b2f(v[i]), sl[cc * 2], sl[cc * 2 + 1]), 0.f);
        }
        __syncthreads();
        f4 o0, o1;
#pragma unroll
        for (int i = 0; i < 4; i++) { o0[i] = tile[c][p0 + i]; o1[i] = tile[c][p0 + 4 + i]; }
        float* dst = ob + (size_t)c * NF + n0 + p0;
        *(f4*)dst = o0;
        *(f4*)(dst + 4) = o1;
    }
}

extern "C" void kernel_launch(void* const* d_in, const int* in_sizes, int n_in,
                              void* d_out, int out_size, void* d_ws, size_t ws_size,
                              hipStream_t stream)
{
    const float* x1 = (const float*)d_in[0];
    const float* x2 = (const float*)d_in[1];
    const float* wr = (const float*)d_in[2];
    const float* gA = (const float*)d_in[3];
    const float* bA = (const float*)d_in[4];
    const float* w1 = (const float*)d_in[5];
    const float* g1 = (const float*)d_in[6];
    const float* b1 = (const float*)d_in[7];
    const float* w2 = (const float*)d_in[8];
    const float* g2 = (const float*)d_in[9];
    const float* b2 = (const float*)d_in[10];
    const int* sidx = (const int*)d_in[11];
    const int* uidx = (const int*)d_in[12];
    const int* nbr  = (const int*)d_in[13];

    // d_out (102.4 MB): comb [B][NF][64] bf16 -> dead after conv1. Then
    // h2-b0 [NF][32] bf16 at [76.8,102.4) -> consumed by norm2t-b0 before
    // norm2t-b1 writes out-b1 over [51.2,102.4). Final: out f32 [B][32][NF].
    // ws (~59.5 MB): h1 51.2 (b0 slot reused as h2-b1 after conv2-b0) | y 8.19 |
    // stats | wf tables.
    char* ws = (char*)d_ws;
    u16* h1      = (u16*)ws;                            // [B][NF][32] bf16
    u16* y       = (u16*)(ws + 51200000);               // [B][SVOX][32] bf16
    float* stats = (float*)(ws + 59392000);             // 3 x 16 KB padded accumulators
    float* statsA = stats;
    float* stats1 = (float*)(ws + 59392000 + 16384);
    float* stats2 = (float*)(ws + 59392000 + 32768);
    u16* wf1g = (u16*)(ws + 59392000 + 49152);          // 28672 B
    u16* wf2g = (u16*)(ws + 59392000 + 49152 + 28672);  // 14336 B
    u16* comb  = (u16*)d_out;
    u16* h2b0  = (u16*)((char*)d_out + 76800000);       // [NF][32] bf16, 25.6 MB
    u16* h2b1  = (u16*)ws;                              // h1-b0 slot, dead after conv2-b0

    k_prep<<<48, 256, 0, stream>>>(w1, w2, stats, wf1g, wf2g);
    k_reduce<<<dim3(125, BB), 256, 0, stream>>>(x1, wr, y, statsA);
    k_build<<<dim3(1024, BB), 256, 0, stream>>>(x2, y, statsA, gA, bA, sidx, uidx, comb);
    k_conv1<<<dim3(3125, BB), 512, 0, stream>>>(comb, wf1g, nbr, h1, stats1);
    k_conv2<<<3125, 512, 0, stream>>>(h1, wf2g, nbr, stats1, g1, b1, h2b0, stats2, 0);
    k_conv2<<<3125, 512, 0, stream>>>(h1, wf2g, nbr, stats1, g1, b1, h2b1, stats2, 1);
    k_norm2t<<<2048, 256, 0, stream>>>(h2b0, stats2, g2, b2, (float*)d_out, 0);
    k_norm2t<<<2048, 256, 0, stream>>>(h2b1, stats2, g2, b2, (float*)d_out, 1);
}